// Round 5
// baseline (112.197 us; speedup 1.0000x reference)
//
#include <hip/hip_runtime.h>

#define FRAME 160
#define ORDER 12
#define NFRAMES (4096 * 15)
#define EPL 10            // elements per lane (16 lanes per frame)
#define FPW 4             // frames per wave
#define PADF 12           // zero front-pad per frame row (FIR history)
#define ROWL (PADF + FRAME)

template<int CTRL>
__device__ __forceinline__ float dppf(float v) {
    return __int_as_float(__builtin_amdgcn_update_dpp(
        0, __float_as_int(v), CTRL, 0xF, 0xF, true));
}

// Sum across each 16-lane row, pure-VALU DPP; bit-identical in all 16 lanes.
__device__ __forceinline__ float rowsum16(float v) {
    v += dppf<0xB1>(v);    // quad_perm [1,0,3,2]  : lane ^= 1
    v += dppf<0x4E>(v);    // quad_perm [2,3,0,1]  : lane ^= 2
    v += dppf<0x140>(v);   // row_mirror
    v += dppf<0x141>(v);   // row_half_mirror
    return v;
}

__global__ __launch_bounds__(256, 8) void ResidualEmbedding_70798240907390_kernel(
    const int* __restrict__ bits, const float* __restrict__ pcm,
    const float* __restrict__ alpha_p, float* __restrict__ out)
{
    const int tid  = threadIdx.x;
    const int wave = tid >> 6;
    const int lane = tid & 63;
    const int g    = lane >> 4;
    const int s    = lane & 15;
    const int wf0  = (blockIdx.x * 4 + wave) * FPW;
    const int f_id = wf0 + g;

    __shared__ float s_win[161];                  // Hann + win[160]=0 pad
    __shared__ float s_x[4][FPW * ROWL + 1];      // 12-zero front pad per frame
    __shared__ float s_a[4][FPW][16];

    if (tid < 161) {
        float w = (tid < 160)
            ? 0.5f - 0.5f * __cosf(6.2831853071795864769f / 159.0f * (float)tid)
            : 0.0f;
        s_win[tid] = w;
    }
    if (lane < FPW * PADF) {
        int fr = lane / PADF, sl = lane % PADF;
        s_x[wave][fr * ROWL + sl] = 0.0f;
    }
    if (lane == 63) s_x[wave][FPW * ROWL] = 0.0f;
    {
        const float4* src = (const float4*)(pcm + (size_t)wf0 * FRAME);
#pragma unroll
        for (int it = 0; it < 3; ++it) {
            int id = lane + 64 * it;              // 0..191
            if (id < 160) {
                int fr = id / 40, ix = id % 40;
                *(float4*)&s_x[wave][fr * ROWL + PADF + 4 * ix] = src[fr * 40 + ix];
            }
        }
    }
    __syncthreads();

    const float* Xr = &s_x[wave][g * ROWL];       // Xr[PADF + n] = x[n]
    const int p0 = s * EPL;

    // Prefetch embed scalars early (hide global latency behind Burg).
    const float ac = alpha_p[0] * (2.0f * (float)bits[f_id] - 1.0f);

    // b[p]=xw[p], f[p]=xw[p+1]; position 159 zero (invariant).
    float F[EPL], B[EPL];
    {
        float pr[EPL + 1];
#pragma unroll
        for (int j = 0; j <= EPL; ++j)
            pr[j] = Xr[PADF + p0 + j] * s_win[p0 + j];
#pragma unroll
        for (int t = 0; t < EPL; ++t) { F[t] = pr[t + 1]; B[t] = pr[t]; }
    }
    B[EPL - 1] = (s == 15) ? 0.0f : B[EPL - 1];
    float dp0 = 0.0f, dp1 = 0.0f;
#pragma unroll
    for (int t = 0; t < EPL; ++t) {
        dp0 = fmaf(F[t], F[t], dp0);
        dp1 = fmaf(B[t], B[t], dp1);
    }
    float den = rowsum16(dp0 + dp1);

    // a (lane s holds a[s]) and pivot-reversal ar[s] = a[i+1-s].
    float a  = (s == 0) ? 1.0f : 0.0f;
    float ar = (s == 1) ? 1.0f : 0.0f;
    float cpart = 0.0f, denScaled = 0.0f;

#pragma unroll
    for (int i = 0; i < ORDER; ++i) {
        float q0 = 0.0f, q1 = 0.0f;
#pragma unroll
        for (int t = 0; t < EPL; t += 2) {
            q0 = fmaf(F[t],     B[t],     q0);
            q1 = fmaf(F[t + 1], B[t + 1], q1);
        }
        float num = rowsum16(q0 + q1);
        if (i > 0) den = denScaled - rowsum16(cpart);
        float r = -2.0f * num * __builtin_amdgcn_rcpf(den);

        // a[:i+2] += r*a[:i+2][::-1]:  a'=a+r*ar ; ar'=(ar+r*a)>>1 lane
        float a_new  = fmaf(r, ar, a);
        float ar_new = fmaf(r, a, ar);
        a  = a_new;
        ar = dppf<0x111>(ar_new);                 // row_shr:1, lane0 <- 0

        // In-place lattice update (no nF/nB arrays: -20 live VGPRs).
#pragma unroll
        for (int t = 0; t < EPL; ++t) {
            float fo = F[t];
            F[t] = fmaf(r, B[t], fo);
            B[t] = fmaf(r, fo, B[t]);
        }

        const int pe = 158 - i;                   // compile-time (full unroll)
        const int SL = pe / EPL, SS = pe % EPL;
        float fe = (s == 0)  ? F[0]  : 0.0f;      // f'[0]
        float be = (s == SL) ? B[SS] : 0.0f;      // b'[last]
        cpart = fmaf(fe, fe, be * be);
        denScaled = fmaf(-r * r, den, den);

        // f = f'[1:]  (row_shl:1 brings lane s+1's F[0]; lane15 -> 0)
        float up = dppf<0x101>(F[0]);
#pragma unroll
        for (int t = 0; t < EPL - 1; ++t) F[t] = F[t + 1];
        F[EPL - 1] = up;
        // b = b'[:-1] (zero newly-invalid slot; keeps maskless-dot invariant)
        B[SS] = (s == SL) ? 0.0f : B[SS];
    }

    // Broadcast a[0..12] within the group via LDS bounce.
    s_a[wave][g][s] = a;
    __syncthreads();
    float ak[ORDER + 1];
#pragma unroll
    for (int k = 0; k <= ORDER; ++k) ak[k] = s_a[wave][g][k];

    // FIR window from padded LDS as float2 (8B-aligned: 688g + 40s).
    float Xw[EPL + ORDER];
    {
        const float2* Xp = (const float2*)(Xr + p0);
#pragma unroll
        for (int j = 0; j < (EPL + ORDER) / 2; ++j) {
            float2 v = Xp[j];
            Xw[2 * j] = v.x; Xw[2 * j + 1] = v.y;
        }
    }

    float2* og = (float2*)(out + (size_t)f_id * FRAME + p0);
#pragma unroll
    for (int t = 0; t < EPL; t += 2) {
        float acc0 = 0.0f, acc1 = 0.0f;
#pragma unroll
        for (int k = 0; k <= ORDER; ++k) {
            acc0 = fmaf(ak[k], Xw[ORDER + t - k],     acc0);
            acc1 = fmaf(ak[k], Xw[ORDER + t + 1 - k], acc1);
        }
        og[t / 2] = make_float2(fmaf(ac, acc0, Xw[ORDER + t]),
                                fmaf(ac, acc1, Xw[ORDER + t + 1]));
    }
}

extern "C" void kernel_launch(void* const* d_in, const int* in_sizes, int n_in,
                              void* d_out, int out_size, void* d_ws, size_t ws_size,
                              hipStream_t stream) {
    const int*   bits  = (const int*)d_in[0];
    const float* pcm   = (const float*)d_in[1];
    const float* alpha = (const float*)d_in[2];
    float*       out   = (float*)d_out;

    dim3 grid(NFRAMES / 16), block(256);
    hipLaunchKernelGGL(ResidualEmbedding_70798240907390_kernel, grid, block, 0, stream,
                       bits, pcm, alpha, out);
}

// Round 6
// 105.008 us; speedup vs baseline: 1.0685x; 1.0685x over previous
//
#include <hip/hip_runtime.h>

#define FRAME 160
#define ORDER 12
#define NFRAMES (4096 * 15)
#define EPL 10            // elements per sub-lane (16 lanes per frame-pair)
#define ROWP 174          // 12 front pad + 160 + 1 zero tail + 1 align pad (16B row stride)

typedef float v2f __attribute__((ext_vector_type(2)));

__device__ __forceinline__ v2f pkfma(v2f a, v2f b, v2f c) {
    return __builtin_elementwise_fma(a, b, c);
}
__device__ __forceinline__ v2f splat2(float v) { v2f r; r.x = v; r.y = v; return r; }

template<int CTRL>
__device__ __forceinline__ float dppf(float v) {
    return __int_as_float(__builtin_amdgcn_update_dpp(
        0, __float_as_int(v), CTRL, 0xF, 0xF, true));
}

// Sum across each 16-lane row, pure-VALU DPP; bit-identical in all 16 lanes.
__device__ __forceinline__ float rowsum16(float v) {
    v += dppf<0xB1>(v);    // quad_perm [1,0,3,2]  : lane ^= 1
    v += dppf<0x4E>(v);    // quad_perm [2,3,0,1]  : lane ^= 2
    v += dppf<0x140>(v);   // row_mirror
    v += dppf<0x141>(v);   // row_half_mirror
    return v;
}
__device__ __forceinline__ v2f rowsum16v(v2f v) {  // two independent chains (ILP x2)
    v2f r; r.x = rowsum16(v.x); r.y = rowsum16(v.y); return r;
}

__global__ __launch_bounds__(256) void ResidualEmbedding_70798240907390_kernel(
    const int* __restrict__ bits, const float* __restrict__ pcm,
    const float* __restrict__ alpha_p, float* __restrict__ out)
{
    const int tid  = threadIdx.x;
    const int wave = tid >> 6;
    const int lane = tid & 63;
    const int g    = lane >> 4;          // frame-PAIR group within wave
    const int s    = lane & 15;
    const int wf0  = (blockIdx.x * 4 + wave) * 8;   // 8 frames per wave
    const int fA   = wf0 + 2 * g;
    const int fB   = fA + 1;

    // s_x[w][g][12+p] = {xA[p], xB[p]}; rows 16B-aligned (ROWP even).
    __shared__ __align__(16) v2f s_x[4][4][ROWP];
    __shared__ float s_win[161];
    __shared__ v2f  s_a[4][4][16];

    // Hann window once per block; win[160]=0 kills the tail edge case.
    if (tid < 161) {
        float w = (tid < 160)
            ? 0.5f - 0.5f * __cosf(6.2831853071795864769f / 159.0f * (float)tid)
            : 0.0f;
        s_win[tid] = w;
    }
    // Zero front pads (12 pairs x 4 rows) and tail pad (1 pair x 4 rows).
    if (lane < 48) { int gr = lane / 12, j = lane % 12; s_x[wave][gr][j] = splat2(0.f); }
    if (lane < 4)  s_x[wave][lane][172] = splat2(0.f);

    // Stage: coalesced float4 per frame, written pair-interleaved as 2x b128.
    {
        const float* pAg = pcm + (size_t)fA * FRAME;
        const float* pBg = pcm + (size_t)fB * FRAME;
#pragma unroll
        for (int c = 0; c < 3; ++c) {
            int p = 4 * s + 64 * c;
            if (p < FRAME) {
                float4 a4 = *(const float4*)(pAg + p);
                float4 b4 = *(const float4*)(pBg + p);
                float4* dst = (float4*)&s_x[wave][g][12 + p];   // 16B aligned
                dst[0] = make_float4(a4.x, b4.x, a4.y, b4.y);
                dst[1] = make_float4(a4.z, b4.z, a4.w, b4.w);
            }
        }
    }
    __syncthreads();

    const v2f* X = &s_x[wave][g][12];    // X[p] = {xA[p], xB[p]}, p in [-12, 160]
    const int p0 = s * EPL;

    // Windowed products; b[p]=xw[p], f[p]=xw[p+1]; position 159 zero invariant
    // (X[160] = 0 via tail pad AND win[160] = 0).
    v2f F[EPL], B[EPL];
    {
        v2f pr[EPL + 1];
#pragma unroll
        for (int j = 0; j <= EPL; ++j)
            pr[j] = X[p0 + j] * s_win[p0 + j];
#pragma unroll
        for (int t = 0; t < EPL; ++t) { F[t] = pr[t + 1]; B[t] = pr[t]; }
    }
    if (s == 15) B[EPL - 1] = splat2(0.f);
    v2f dpF = splat2(0.f), dpB = splat2(0.f);
#pragma unroll
    for (int t = 0; t < EPL; ++t) {
        dpF = pkfma(F[t], F[t], dpF);
        dpB = pkfma(B[t], B[t], dpB);
    }
    v2f den = rowsum16v(dpF + dpB);

    v2f a  = (s == 0) ? splat2(1.f) : splat2(0.f);
    v2f ar = (s == 1) ? splat2(1.f) : splat2(0.f);
    v2f cp = splat2(0.f), dsc = splat2(0.f);

#pragma unroll
    for (int i = 0; i < ORDER; ++i) {
        v2f q0 = splat2(0.f), q1 = splat2(0.f);
#pragma unroll
        for (int t = 0; t < EPL; t += 2) {
            q0 = pkfma(F[t],     B[t],     q0);
            q1 = pkfma(F[t + 1], B[t + 1], q1);
        }
        v2f num = rowsum16v(q0 + q1);
        if (i > 0) den = dsc - rowsum16v(cp);
        v2f r;
        r.x = -2.0f * num.x * __builtin_amdgcn_rcpf(den.x);
        r.y = -2.0f * num.y * __builtin_amdgcn_rcpf(den.y);

        // a[:i+2] += r*a[:i+2][::-1]:  a'=a+r*ar ; ar'=(ar+r*a)>>1 lane
        v2f an  = pkfma(r, ar, a);
        v2f arn = pkfma(r, a, ar);
        a = an;
        ar.x = dppf<0x111>(arn.x);       // row_shr:1, lane0 <- 0
        ar.y = dppf<0x111>(arn.y);

        // In-place lattice update (each pk op serves BOTH frames).
#pragma unroll
        for (int t = 0; t < EPL; ++t) {
            v2f fo = F[t];
            F[t] = pkfma(r, B[t], fo);
            B[t] = pkfma(r, fo, B[t]);
        }

        const int pe = 158 - i;          // compile-time (full unroll)
        const int SL = pe / EPL, SS = pe % EPL;
        v2f fe = (s == 0)  ? F[0]  : splat2(0.f);
        v2f be = (s == SL) ? B[SS] : splat2(0.f);
        cp  = pkfma(fe, fe, be * be);
        dsc = pkfma(-(r * r), den, den); // (1-r^2)*den

        // f = f'[1:]  (row_shl:1; lane15 -> 0 keeps invariant)
        v2f up;
        up.x = dppf<0x101>(F[0].x);
        up.y = dppf<0x101>(F[0].y);
#pragma unroll
        for (int t = 0; t < EPL - 1; ++t) F[t] = F[t + 1];
        F[EPL - 1] = up;
        if (s == SL) B[SS] = splat2(0.f);
    }

    // Broadcast packed a[0..12] within the group via LDS bounce.
    s_a[wave][g][s] = a;
    __syncthreads();
    v2f ak[ORDER + 1];
#pragma unroll
    for (int k = 0; k <= ORDER; ++k) ak[k] = s_a[wave][g][k];

    // FIR window straight from pair-interleaved LDS (front pad = zero history).
    v2f Xw[EPL + ORDER];
#pragma unroll
    for (int j = 0; j < EPL + ORDER; ++j) Xw[j] = X[p0 - ORDER + j];

    const float alpha = alpha_p[0];
    v2f ac;
    ac.x = alpha * (2.0f * (float)bits[fA] - 1.0f);
    ac.y = alpha * (2.0f * (float)bits[fB] - 1.0f);

    float* oA = out + (size_t)fA * FRAME + p0;
    float* oB = out + (size_t)fB * FRAME + p0;
#pragma unroll
    for (int t = 0; t < EPL; t += 2) {
        v2f acc0 = splat2(0.f), acc1 = splat2(0.f);
#pragma unroll
        for (int k = 0; k <= ORDER; ++k) {
            acc0 = pkfma(ak[k], Xw[ORDER + t - k],     acc0);
            acc1 = pkfma(ak[k], Xw[ORDER + t + 1 - k], acc1);
        }
        v2f r0 = pkfma(ac, acc0, Xw[ORDER + t]);
        v2f r1 = pkfma(ac, acc1, Xw[ORDER + t + 1]);
        *(float2*)(oA + t) = make_float2(r0.x, r1.x);
        *(float2*)(oB + t) = make_float2(r0.y, r1.y);
    }
}

extern "C" void kernel_launch(void* const* d_in, const int* in_sizes, int n_in,
                              void* d_out, int out_size, void* d_ws, size_t ws_size,
                              hipStream_t stream) {
    const int*   bits  = (const int*)d_in[0];
    const float* pcm   = (const float*)d_in[1];
    const float* alpha = (const float*)d_in[2];
    float*       out   = (float*)d_out;

    // 61440 frames; 32 per block (4 waves x 4 groups x 2 packed frames).
    dim3 grid(NFRAMES / 32), block(256);
    hipLaunchKernelGGL(ResidualEmbedding_70798240907390_kernel, grid, block, 0, stream,
                       bits, pcm, alpha, out);
}